// Round 8
// baseline (613.508 us; speedup 1.0000x reference)
//
#include <hip/hip_runtime.h>

// DEPTree gfx950 — Round 8: 7 dispatches.
// D1 = W convert (256 blk) || per-block hist (171 blk, LDS only).
// D2 = scatter+plan (171 blk; block0 writes tile tables).
// D3 = stage1 MFMA GEMM. D4 = L6. D5 = L5. D6 = L4.
// D7 = tail: L3+L2 (MFMA tiles, 4 teams) + L1+L0 (bf16 GEMV) + final, one block.

#define DD 128
#define NN 21845
#define NPOS 18
#define NDEP 46
#define NB 248            // 18 pos + 5*46 dep buckets (parent levels 2..6)
#define NCHALL 21844
#define CH_LO 20          // first bucketed child flat index (level-3 nodes)
#define NITEMS (NN + NCHALL - CH_LO)   // 43669
#define NHB 171

typedef __attribute__((ext_vector_type(8))) short short8;
typedef __attribute__((ext_vector_type(4))) float f32x4;

__device__ __forceinline__ unsigned short f2bf(float f) {
    union { float f; unsigned int u; } v; v.f = f;
    unsigned int r = v.u + 0x7fffu + ((v.u >> 16) & 1u);   // RNE
    return (unsigned short)(r >> 16);
}
__device__ __forceinline__ float bf2f(unsigned short s) {
    union { unsigned int u; float f; } v; v.u = ((unsigned int)s) << 16;
    return v.f;
}

// decode item g -> bucket b, payload
__device__ __forceinline__ void decode_item(int g, const int* __restrict__ pos_ids,
                                            const int* __restrict__ dep_ids,
                                            int& b, int& payload) {
    if (g < NN) {
        b = pos_ids[g]; payload = g;
    } else {
        int j = g - NN + CH_LO;
        int base = CH_LO, sz = 64, l = 2;
        while (j >= base + sz) { base += sz; sz <<= 2; ++l; }
        int c = j - base;
        b = NPOS + (l - 2) * NDEP + dep_ids[base + 1 + c];
        payload = c;
    }
}

// ---- D1: blocks 0..255 convert W -> bf16 transposed [mat][n][k];
//          blocks 256..426 per-block histogram -> blk_cnt ----
__global__ __launch_bounds__(256) void conv_hist_kernel(
        const float* __restrict__ posW, const float* __restrict__ depW,
        unsigned short* __restrict__ Wt,
        const int* __restrict__ pos_ids, const int* __restrict__ dep_ids,
        int* __restrict__ blk_cnt) {
    __shared__ __align__(16) char smem[9216];
    int bid = blockIdx.x, tid = threadIdx.x;
    if (bid < 256) {
        unsigned short (*lds)[72] = (unsigned short (*)[72])smem;
        int mat = bid >> 2, tile = bid & 3;
        int tk = (tile >> 1) * 64, tn = (tile & 1) * 64;
        const float* W = (mat < NPOS) ? (posW + (size_t)mat * DD * DD)
                                      : (depW + (size_t)(mat - NPOS) * DD * DD);
        unsigned short* O = Wt + (size_t)mat * DD * DD;
        int tx = tid & 63, ty = tid >> 6;
#pragma unroll
        for (int i = 0; i < 16; ++i) {
            int r = ty + i * 4;
            lds[tx][r] = f2bf(W[(size_t)(tk + r) * DD + tn + tx]);
        }
        __syncthreads();
#pragma unroll
        for (int i = 0; i < 16; ++i) {
            int r = ty + i * 4;
            O[(size_t)(tn + r) * DD + tk + tx] = lds[r][tx];
        }
    } else {
        int* h = (int*)smem;
        for (int i = tid; i < NB; i += 256) h[i] = 0;
        __syncthreads();
        int hb = bid - 256;
        int g = hb * 256 + tid;
        if (g < NITEMS) {
            int b, payload;
            decode_item(g, pos_ids, dep_ids, b, payload);
            atomicAdd(&h[b], 1);
        }
        __syncthreads();
        for (int i = tid; i < NB; i += 256)
            blk_cnt[hb * NB + i] = h[i];
    }
}

// ---- D2: scatter + plan (171 blocks). block0 also writes tile tables ----
__global__ __launch_bounds__(256) void plan_scatter_kernel(
        const int* __restrict__ pos_ids, const int* __restrict__ dep_ids,
        const int* __restrict__ blk_cnt, int* __restrict__ perm_pos,
        int* __restrict__ perm_dep, int* __restrict__ ntiles,
        int2* __restrict__ tbl1, int2* __restrict__ tblL) {
    __shared__ int tot[NB], pre[NB], scb[NB], tpre[NB], rank[NB];
    int bid = blockIdx.x, tid = threadIdx.x;
    if (tid < NB) {
        int sa = 0, sb = 0;
        for (int bb = 0; bb < NHB; ++bb) {
            int v = blk_cnt[bb * NB + tid];
            sa += v;
            if (bb < bid) sb += v;
        }
        tot[tid] = sa; pre[tid] = sb; rank[tid] = 0;
    }
    __syncthreads();
    if (tid < NB) {
        const int gbase[5] = {20, 84, 340, 1364, 5460};  // dep groups: levels 2..6
        int gs, base;
        if (tid < NPOS) { gs = 0; base = 0; }
        else {
            int g = (tid - NPOS) / NDEP;
            gs = NPOS + g * NDEP; base = gbase[g];
        }
        int off = base, tp = 0;
        for (int j = gs; j < tid; ++j) {
            off += tot[j];
            tp += (tot[j] + 63) >> 6;
        }
        scb[tid] = off; tpre[tid] = tp;
        bool last = (tid == NPOS - 1) ||
                    (tid >= NPOS && ((tid - NPOS) % NDEP == NDEP - 1));
        if (bid == 0 && last) {
            int g = (tid < NPOS) ? 0 : 1 + (tid - NPOS) / NDEP;
            ntiles[g] = tp + ((tot[tid] + 63) >> 6);
        }
    }
    __syncthreads();
    if (bid == 0 && tid < NB) {
        int b = tid;
        int g = (b < NPOS) ? 0 : 1 + (b - NPOS) / NDEP;
        int loc = (b < NPOS) ? b : (b - NPOS) % NDEP;
        int2* tb = (g == 0) ? tbl1 : tblL + (g - 1) * 302;
        int c = tot[b], t = (c + 63) >> 6;
        for (int k = 0; k < t; ++k) {
            int2 ent;
            ent.x = loc | (min(64, c - (k << 6)) << 8);
            ent.y = scb[b] + (k << 6);
            tb[tpre[b] + k] = ent;
        }
    }
    int g = bid * 256 + tid;
    if (g < NITEMS) {
        int b, payload;
        decode_item(g, pos_ids, dep_ids, b, payload);
        int local = atomicAdd(&rank[b], 1);
        int idx = scb[b] + pre[b] + local;
        if (b < NPOS) perm_pos[idx] = payload;
        else perm_dep[idx] = payload;
    }
}

// ---- 64-row x 128-col MFMA tile over 256 threads (4 waves) ----
// MODE 0: A = bf16(emb[perm[r]]); MODE 1: A = xb[perm[r]];
// MODE 2: A = max(xb[c], uprev[4c+j])
template <int MODE>
__device__ __forceinline__ void gemm_tile(
        int2 e, const int* __restrict__ perm, const unsigned short* __restrict__ Wt,
        const float* __restrict__ bias, const float* __restrict__ embf,
        const unsigned short* __restrict__ xb, const unsigned short* __restrict__ uprev,
        unsigned short* __restrict__ outr, int ltid) {
    int bucket = e.x & 255;
    int rows = e.x >> 8;
    int rowstart = e.y;
    int lane = ltid & 63;
    int w = ltid >> 6;
    int lr = lane & 15;
    int kk = (lane >> 4) * 8;
    const short8 zero8 = {0, 0, 0, 0, 0, 0, 0, 0};

    int m_a = w * 16 + lr;
    bool valid_a = m_a < rows;
    int rid_a = valid_a ? perm[rowstart + m_a] : 0;

    short8 afr[4];
    if (MODE == 0) {
        const float* ar = embf + (size_t)rid_a * DD + kk;
#pragma unroll
        for (int s = 0; s < 4; ++s) {
            float4 lo = *(const float4*)(ar + s * 32);
            float4 hi = *(const float4*)(ar + s * 32 + 4);
            short8 a;
            a[0] = (short)f2bf(lo.x); a[1] = (short)f2bf(lo.y);
            a[2] = (short)f2bf(lo.z); a[3] = (short)f2bf(lo.w);
            a[4] = (short)f2bf(hi.x); a[5] = (short)f2bf(hi.y);
            a[6] = (short)f2bf(hi.z); a[7] = (short)f2bf(hi.w);
            afr[s] = valid_a ? a : zero8;
        }
    } else if (MODE == 1) {
        const unsigned short* ar = xb + (size_t)rid_a * DD + kk;
#pragma unroll
        for (int s = 0; s < 4; ++s)
            afr[s] = valid_a ? *(const short8*)(ar + s * 32) : zero8;
    } else {
        const unsigned short* xr = xb + (size_t)rid_a * DD + kk;
        const unsigned short* ur = uprev + (size_t)(4 * rid_a) * DD + kk;
#pragma unroll
        for (int s = 0; s < 4; ++s) {
            short8 a = *(const short8*)(xr + s * 32);
#pragma unroll
            for (int j = 0; j < 4; ++j) {
                short8 u = *(const short8*)(ur + j * DD + s * 32);
#pragma unroll
                for (int q = 0; q < 8; ++q)
                    if ((unsigned short)u[q] > (unsigned short)a[q]) a[q] = u[q];
            }
            afr[s] = valid_a ? a : zero8;
        }
    }

    f32x4 acc[8];
#pragma unroll
    for (int t = 0; t < 8; ++t) acc[t] = (f32x4){0.f, 0.f, 0.f, 0.f};

    const unsigned short* Wb = Wt + (size_t)bucket * DD * DD;
#pragma unroll
    for (int s = 0; s < 4; ++s) {
        short8 bfr[8];
#pragma unroll
        for (int t = 0; t < 8; ++t)
            bfr[t] = *(const short8*)(Wb + (size_t)(t * 16 + lr) * DD + s * 32 + kk);
#pragma unroll
        for (int t = 0; t < 8; ++t)
            acc[t] = __builtin_amdgcn_mfma_f32_16x16x32_bf16(afr[s], bfr[t], acc[t], 0, 0, 0);
    }

    int rq[4]; bool vq[4];
#pragma unroll
    for (int q = 0; q < 4; ++q) {
        int m = w * 16 + (lane >> 4) * 4 + q;
        vq[q] = m < rows;
        rq[q] = vq[q] ? perm[rowstart + m] : 0;
    }
    const float* bb = bias + bucket * DD;
#pragma unroll
    for (int t = 0; t < 8; ++t) {
        int col = t * 16 + lr;
        float bv = bb[col];
#pragma unroll
        for (int q = 0; q < 4; ++q) {
            if (vq[q]) {
                float v = fmaxf(acc[t][q] + bv, 0.f);
                outr[(size_t)rq[q] * DD + col] = f2bf(v);
            }
        }
    }
}

template <int MODE>
__global__ __launch_bounds__(256) void gemm_kernel(
        const int2* __restrict__ tbl, const int* __restrict__ ntp,
        const int* __restrict__ perm, const unsigned short* __restrict__ Wt,
        const float* __restrict__ bias, const float* __restrict__ embf,
        const unsigned short* __restrict__ xb, const unsigned short* __restrict__ uprev,
        unsigned short* __restrict__ outr) {
    if ((int)blockIdx.x >= ntp[0]) return;
    gemm_tile<MODE>(tbl[blockIdx.x], perm, Wt, bias, embf, xb, uprev, outr,
                    threadIdx.x);
}

// ---- D7 tail: L3, L2 (MFMA tiles, 4 teams of 256), L1, L0 (bf16 GEMV), final
__global__ __launch_bounds__(1024) void tail_kernel(
        const int2* __restrict__ tblL, const int* __restrict__ ntiles,
        const int* __restrict__ perm_dep, const int* __restrict__ dep_ids,
        const unsigned short* __restrict__ Wtd, const float* __restrict__ dep_b,
        const unsigned short* __restrict__ xbf, unsigned short* __restrict__ uarena,
        float* __restrict__ out) {
    __shared__ float zbuf[16][DD];
    int tid = threadIdx.x;
    int team = tid >> 8, ltid = tid & 255;
    unsigned short* uL4 = uarena + (size_t)20480 * DD;
    unsigned short* uL3 = uarena + (size_t)21504 * DD;
    unsigned short* uL2 = uarena + (size_t)21760 * DD;
    unsigned short* uL1 = uarena + (size_t)21824 * DD;
    unsigned short* uL0 = uarena + (size_t)21840 * DD;

    // L3: parent level 3 (group index 2 -> tblL + 1*302)
    int nt3 = ntiles[2];
    for (int t = team; t < nt3; t += 4)
        gemm_tile<2>(tblL[1 * 302 + t], perm_dep, Wtd, dep_b, nullptr,
                     xbf + (size_t)85 * DD, uL4, uL3, ltid);
    __syncthreads();
    // L2: parent level 2 (group index 1 -> tblL + 0*302)
    int nt2 = ntiles[1];
    for (int t = team; t < nt2; t += 4)
        gemm_tile<2>(tblL[0 * 302 + t], perm_dep, Wtd, dep_b, nullptr,
                     xbf + (size_t)21 * DD, uL3, uL2, ltid);
    __syncthreads();

    // L1: 16 GEMVs (children at level 2, rows x[5..20], did=dep_ids[5+c])
    {
        int c = tid >> 7, e = tid & 127;   // c in 0..7, two rounds
#pragma unroll
        for (int r = 0; r < 2; ++r) {
            int cc = c + r * 8;
            unsigned short m = xbf[(size_t)(5 + cc) * DD + e];
#pragma unroll
            for (int j = 0; j < 4; ++j) {
                unsigned short u = uL2[(size_t)(4 * cc + j) * DD + e];
                if (u > m) m = u;
            }
            zbuf[cc][e] = bf2f(m);
        }
        __syncthreads();
#pragma unroll
        for (int r = 0; r < 2; ++r) {
            int cc = c + r * 8;
            int did = dep_ids[5 + cc];
            const unsigned short* Wr = Wtd + (size_t)did * DD * DD + (size_t)e * DD;
            float a = dep_b[did * DD + e];
#pragma unroll
            for (int s = 0; s < 16; ++s) {
                short8 w8 = *(const short8*)(Wr + s * 8);
#pragma unroll
                for (int q = 0; q < 8; ++q)
                    a = fmaf(zbuf[cc][s * 8 + q], bf2f((unsigned short)w8[q]), a);
            }
            uL1[(size_t)cc * DD + e] = f2bf(fmaxf(a, 0.f));
        }
        __syncthreads();
    }
    // L0: 4 GEMVs (children at level 1, rows x[1..4], did=dep_ids[1+c])
    {
        int c = tid >> 7, e = tid & 127;
        if (c < 4) {
            unsigned short m = xbf[(size_t)(1 + c) * DD + e];
#pragma unroll
            for (int j = 0; j < 4; ++j) {
                unsigned short u = uL1[(size_t)(4 * c + j) * DD + e];
                if (u > m) m = u;
            }
            zbuf[c][e] = bf2f(m);
        }
        __syncthreads();
        if (c < 4) {
            int did = dep_ids[1 + c];
            const unsigned short* Wr = Wtd + (size_t)did * DD * DD + (size_t)e * DD;
            float a = dep_b[did * DD + e];
#pragma unroll
            for (int s = 0; s < 16; ++s) {
                short8 w8 = *(const short8*)(Wr + s * 8);
#pragma unroll
                for (int q = 0; q < 8; ++q)
                    a = fmaf(zbuf[c][s * 8 + q], bf2f((unsigned short)w8[q]), a);
            }
            uL0[(size_t)c * DD + e] = f2bf(fmaxf(a, 0.f));
        }
        __syncthreads();
    }
    // final
    if (tid < DD) {
        unsigned short m = xbf[tid];
#pragma unroll
        for (int j = 0; j < 4; ++j) {
            unsigned short u = uL0[(size_t)j * DD + tid];
            if (u > m) m = u;
        }
        out[tid] = bf2f(m);
    }
}

extern "C" void kernel_launch(void* const* d_in, const int* in_sizes, int n_in,
                              void* d_out, int out_size, void* d_ws, size_t ws_size,
                              hipStream_t stream) {
    const float* emb     = (const float*)d_in[0];
    const int*   pos_ids = (const int*)d_in[1];
    const int*   dep_ids = (const int*)d_in[2];
    const float* pos_W   = (const float*)d_in[3];
    const float* pos_b   = (const float*)d_in[4];
    const float* dep_W   = (const float*)d_in[5];
    const float* dep_b   = (const float*)d_in[6];
    float* out = (float*)d_out;

    char* p = (char*)d_ws;
    auto alloc = [&](size_t bytes) {
        char* r = p; p += (bytes + 255) & ~(size_t)255; return r;
    };
    int*  blk_cnt  = (int*)alloc((size_t)NHB * NB * 4);
    int*  ntiles   = (int*)alloc(8 * 4);
    int*  perm_pos = (int*)alloc((size_t)NN * 4);
    int*  perm_dep = (int*)alloc((size_t)NCHALL * 4);
    int2* tbl1     = (int2*)alloc(360 * 8);
    int2* tblL     = (int2*)alloc(5 * 302 * 8);
    unsigned short* Wt     = (unsigned short*)alloc((size_t)64 * DD * DD * 2);
    unsigned short* xbf    = (unsigned short*)alloc((size_t)NN * DD * 2);
    unsigned short* uarena = (unsigned short*)alloc((size_t)NCHALL * DD * 2);

    // D1: convert + hist
    conv_hist_kernel<<<256 + NHB, 256, 0, stream>>>(pos_W, dep_W, Wt, pos_ids,
                                                    dep_ids, blk_cnt);
    // D2: scatter + plan
    plan_scatter_kernel<<<NHB, 256, 0, stream>>>(pos_ids, dep_ids, blk_cnt,
                                                 perm_pos, perm_dep, ntiles,
                                                 tbl1, tblL);
    // D3: stage1
    gemm_kernel<0><<<360, 256, 0, stream>>>(tbl1, ntiles + 0, perm_pos, Wt, pos_b,
                                            emb, nullptr, nullptr, xbf);
    const unsigned short* Wtd = Wt + (size_t)NPOS * DD * DD;
    // D4: level 6 (group 5)
    gemm_kernel<1><<<302, 256, 0, stream>>>(tblL + 4 * 302, ntiles + 5, perm_dep,
                                            Wtd, dep_b, nullptr,
                                            xbf + (size_t)5461 * DD, nullptr,
                                            uarena);
    // D5: level 5 (group 4)
    gemm_kernel<2><<<110, 256, 0, stream>>>(tblL + 3 * 302, ntiles + 4, perm_dep,
                                            Wtd, dep_b, nullptr,
                                            xbf + (size_t)1365 * DD, uarena,
                                            uarena + (size_t)16384 * DD);
    // D6: level 4 (group 3)
    gemm_kernel<2><<<62, 256, 0, stream>>>(tblL + 2 * 302, ntiles + 3, perm_dep,
                                           Wtd, dep_b, nullptr,
                                           xbf + (size_t)341 * DD,
                                           uarena + (size_t)16384 * DD,
                                           uarena + (size_t)20480 * DD);
    // D7: tail (L3, L2, L1, L0, final)
    tail_kernel<<<1, 1024, 0, stream>>>(tblL, ntiles, perm_dep, dep_ids, Wtd,
                                        dep_b, xbf, uarena, out);
}